// Round 12
// baseline (291.542 us; speedup 1.0000x reference)
//
#include <hip/hip_runtime.h>

// ---------------------------------------------------------------------------
// GCN 2-layer: h1 = prelu(gcn(x,W1,b1)), h2 = prelu(gcn(h1,W2,b2))
// CSR build with ONE packed 32-bit returning atomic per edge (count<<24 |
// deg q6.18). ~21 G returning-atomics/s is a fabric service-rate cap
// (R5-R10 invariant). Count grid-fused with layer-1 GEMM (group-of-8
// interleave, best measured). spair packed 4B: (src<<15)|q0.15(norm).
// NEW: agg(layer1) + gemm2 fused -- block aggregates 64 nodes, stages bf16
// rows in swizzled LDS, MFMA vs pre-packed W2 -> hb2 (separate buffer, no
// alias with gathered hb). Deletes gemm2 dispatch + 51MB out1 re-read.
// ---------------------------------------------------------------------------

static __device__ __forceinline__ float4 ld4(const float* p) { return *(const float4*)p; }

static __device__ __forceinline__ unsigned short f2bf(float f) {
    unsigned u = __float_as_uint(f);
    u += 0x7fff + ((u >> 16) & 1);          // round-to-nearest-even
    return (unsigned short)(u >> 16);
}
static __device__ __forceinline__ float bf2f(unsigned short h) {
    return __uint_as_float(((unsigned)h) << 16);
}

typedef __attribute__((ext_vector_type(8))) short short8v;
typedef __attribute__((ext_vector_type(4))) float f32x4;

static __device__ __forceinline__ int eidx(const void* ei, int flag, long long idx) {
    if (flag) return (int)((const long long*)ei)[idx];
    return ((const int*)ei)[idx];
}

#define CNT_SH 24
#define DEG_SCALE 262144.0f            // 2^18
#define DEG_INV   3.814697265625e-06f  // 2^-18
#define Q15_INV   3.0517578125e-05f    // 2^-15

// --- W pack body: fp32 [128][K] -> bf16 B-fragment layout ------------------
static __device__ __forceinline__ void packW_body(const float* __restrict__ W,
                                                  unsigned short* __restrict__ Bp,
                                                  int t, int kbits) {
    int K = 1 << kbits;
    int col = t >> kbits, k = t & (K - 1);
    int nt = col >> 4, ks = k >> 5;
    int lane = (col & 15) | (((k >> 3) & 3) << 4);
    int j = k & 7;
    Bp[((((size_t)nt * (K >> 5) + ks) * 64 + lane) << 3) + j] = f2bf(W[t]);
}

// --- fused prep: init packed[] + pack W1 + pack W2 + detect dtype ----------
__global__ __launch_bounds__(256) void k_prep(unsigned* __restrict__ packed, int N,
                                              const float* __restrict__ W1,
                                              unsigned short* __restrict__ bp1,
                                              const float* __restrict__ W2,
                                              unsigned short* __restrict__ bp2,
                                              const int* __restrict__ ei_raw,
                                              int* __restrict__ flag,
                                              int nbInit) {
    int b = blockIdx.x;
    if (b < nbInit) {
        int i = b * 256 + threadIdx.x;
        if (i < N) packed[i] = 0u;
    } else if (b < nbInit + 128) {
        int t = (b - nbInit) * 256 + threadIdx.x;       // 128*256 elements
        packW_body(W1, bp1, t, 8);
    } else if (b < nbInit + 192) {
        int t = (b - nbInit - 128) * 256 + threadIdx.x; // 128*128 elements
        packW_body(W2, bp2, t, 7);
    } else {
        __shared__ int anynz;
        if (threadIdx.x == 0) anynz = 0;
        __syncthreads();
        if (ei_raw[2 * threadIdx.x + 1] != 0) anynz = 1;
        __syncthreads();
        if (threadIdx.x == 0) *flag = (anynz == 0) ? 1 : 0;
    }
}

// --- count body: 8 packed returning atomics per thread ---------------------
static __device__ __forceinline__ void count_body(const void* __restrict__ ei,
                                                  const float* __restrict__ ew,
                                                  int flag,
                                                  unsigned* __restrict__ packed,
                                                  unsigned char* __restrict__ rank,
                                                  int E, int cbid) {
    int base = cbid * 2048 + threadIdx.x;
    int d[8]; unsigned inc[8]; bool ok[8];
    #pragma unroll
    for (int u = 0; u < 8; ++u) {
        int e = base + u * 256;
        ok[u] = e < E;
        if (ok[u]) {
            d[u] = eidx(ei, flag, (long long)E + e);
            inc[u] = (1u << CNT_SH) | (unsigned)(ew[e] * DEG_SCALE);
        }
    }
    unsigned old[8];
    #pragma unroll
    for (int u = 0; u < 8; ++u)
        if (ok[u]) old[u] = atomicAdd(&packed[d[u]], inc[u]);
    #pragma unroll
    for (int u = 0; u < 8; ++u)
        if (ok[u]) rank[base + u * 256] = (unsigned char)(old[u] >> CNT_SH);
}

// --- GEMM body (256 thr = 4 waves, 128 rows/block, 32 rows/wave) -----------
template <int K>
static __device__ __forceinline__ void gemm_body(const float* __restrict__ X,
                                                 const unsigned short* __restrict__ Bp,
                                                 unsigned short* __restrict__ Hb,
                                                 int M, int gbid) {
    constexpr int KS = K / 32;
    int wave = threadIdx.x >> 6, lane = threadIdx.x & 63;
    int row0 = gbid * 128 + wave * 32;
    int r0 = row0 + (lane & 15);      if (r0 >= M) r0 = M - 1;
    int r1 = row0 + 16 + (lane & 15); if (r1 >= M) r1 = M - 1;
    int kc = (lane >> 4) * 8;
    const float* x0 = X + (size_t)r0 * K + kc;
    const float* x1 = X + (size_t)r1 * K + kc;

    f32x4 acc[2][8] = {};
    #pragma unroll 2
    for (int ks = 0; ks < KS; ++ks) {
        float4 a0 = ld4(x0 + ks * 32), a1 = ld4(x0 + ks * 32 + 4);
        float4 c0 = ld4(x1 + ks * 32), c1 = ld4(x1 + ks * 32 + 4);
        short8v af0, af1;
        af0[0] = (short)f2bf(a0.x); af0[1] = (short)f2bf(a0.y);
        af0[2] = (short)f2bf(a0.z); af0[3] = (short)f2bf(a0.w);
        af0[4] = (short)f2bf(a1.x); af0[5] = (short)f2bf(a1.y);
        af0[6] = (short)f2bf(a1.z); af0[7] = (short)f2bf(a1.w);
        af1[0] = (short)f2bf(c0.x); af1[1] = (short)f2bf(c0.y);
        af1[2] = (short)f2bf(c0.z); af1[3] = (short)f2bf(c0.w);
        af1[4] = (short)f2bf(c1.x); af1[5] = (short)f2bf(c1.y);
        af1[6] = (short)f2bf(c1.z); af1[7] = (short)f2bf(c1.w);
        #pragma unroll
        for (int nt = 0; nt < 8; ++nt) {
            short8v bf = *(const short8v*)&Bp[(((size_t)nt * KS + ks) * 64 + lane) * 8];
            acc[0][nt] = __builtin_amdgcn_mfma_f32_16x16x32_bf16(af0, bf, acc[0][nt], 0, 0, 0);
            acc[1][nt] = __builtin_amdgcn_mfma_f32_16x16x32_bf16(af1, bf, acc[1][nt], 0, 0, 0);
        }
    }
    // C/D: col = lane&15, row = (lane>>4)*4 + reg   [m89-verified]
    #pragma unroll
    for (int rg = 0; rg < 2; ++rg) {
        int orow0 = row0 + rg * 16 + (lane >> 4) * 4;
        #pragma unroll
        for (int nt = 0; nt < 8; ++nt) {
            int col = nt * 16 + (lane & 15);
            #pragma unroll
            for (int j = 0; j < 4; ++j) {
                int r = orow0 + j;
                if (r < M) Hb[(size_t)r * 128 + col] = f2bf(acc[rg][nt][j]);
            }
        }
    }
}

// --- fused + interleaved: count || layer-1 GEMM ----------------------------
__global__ __launch_bounds__(256) void k_count_gemm1(
        const void* __restrict__ ei, const float* __restrict__ ew,
        const int* __restrict__ flagp, unsigned* __restrict__ packed,
        unsigned char* __restrict__ rank, int E,
        const float* __restrict__ X, const unsigned short* __restrict__ Bp,
        unsigned short* __restrict__ Hb, int M,
        int nbCount, int nbGemm, int cgrps, int ggrps) {
    int grp = blockIdx.x >> 3, ln = blockIdx.x & 7;
    int tot = cgrps + ggrps;
    int cb = (int)(((long long)grp * cgrps) / tot);
    int ca = (int)(((long long)(grp + 1) * cgrps) / tot);
    if (ca > cb) {
        int id = cb * 8 + ln;
        if (id < nbCount) count_body(ei, ew, *flagp, packed, rank, E, id);
    } else {
        int id = (grp - cb) * 8 + ln;
        if (id < nbGemm) gemm_body<256>(X, Bp, Hb, M, id);
    }
}

// --- scan of counts --------------------------------------------------------
__global__ __launch_bounds__(256) void k_blocksum(const unsigned* packed,
                                                  int* bsum, int N) {
    int i = blockIdx.x * 256 + threadIdx.x;
    int v = i < N ? (int)(packed[i] >> CNT_SH) : 0;
    for (int d = 32; d > 0; d >>= 1) v += __shfl_down(v, d, 64);
    __shared__ int wsum[4];
    int lane = threadIdx.x & 63, wid = threadIdx.x >> 6;
    if (lane == 0) wsum[wid] = v;
    __syncthreads();
    if (threadIdx.x == 0) bsum[blockIdx.x] = wsum[0] + wsum[1] + wsum[2] + wsum[3];
}

__global__ __launch_bounds__(512) void k_scan_bsum(int* bsum, int nb) {
    int t = threadIdx.x;
    int v = (t < nb) ? bsum[t] : 0;
    int orig = v;
    int lane = t & 63, wid = t >> 6;
    for (int d = 1; d < 64; d <<= 1) { int n = __shfl_up(v, d, 64); if (lane >= d) v += n; }
    __shared__ int wsum[8];
    if (lane == 63) wsum[wid] = v;
    __syncthreads();
    int woff = 0;
    for (int w = 0; w < 8; ++w) if (w < wid) woff += wsum[w];
    if (t < nb) bsum[t] = v - orig + woff;   // exclusive
}

// scan_final + dinv fused (same index space)
__global__ __launch_bounds__(256) void k_scan_final(const unsigned* packed,
                                                    const int* bsum,
                                                    int* offs, float* dinv,
                                                    int N, int E) {
    int b = blockIdx.x, t = threadIdx.x;
    int i = b * 256 + t;
    unsigned pk = (i < N) ? packed[i] : 0u;
    int v = (int)(pk >> CNT_SH);
    int orig = v;
    int lane = t & 63, wid = t >> 6;
    for (int d = 1; d < 64; d <<= 1) { int n = __shfl_up(v, d, 64); if (lane >= d) v += n; }
    __shared__ int wsum[4];
    if (lane == 63) wsum[wid] = v;
    __syncthreads();
    int woff = bsum[b];
    for (int w = 0; w < 4; ++w) if (w < wid) woff += wsum[w];
    if (i < N) {
        offs[i] = v - orig + woff;
        float dg = 1.0f + (float)(pk & 0xFFFFFFu) * DEG_INV;
        dinv[i] = rsqrtf(dg);
    }
    if (i == 0) offs[N] = E;
}

// --- atomic-free scatter: spair[offs[dst]+rank[e]] = (src<<15)|q15(norm) ---
__global__ __launch_bounds__(256) void k_scatter(const void* __restrict__ ei,
                                                 const float* __restrict__ ew,
                                                 const int* __restrict__ flagp,
                                                 const float* __restrict__ dinv,
                                                 const int* __restrict__ offs,
                                                 const unsigned char* __restrict__ rank,
                                                 unsigned* __restrict__ spair, int E) {
    const int flag = *flagp;
    int e = blockIdx.x * 256 + threadIdx.x;
    if (e < E) {
        int s = eidx(ei, flag, e);
        int d = eidx(ei, flag, (long long)E + e);
        int p = offs[d] + (int)rank[e];
        float nrm = dinv[s] * ew[e] * dinv[d];      // < 0.71 analytically
        unsigned q = (unsigned)(nrm * 32768.0f + 0.5f);
        spair[p] = ((unsigned)s << 15) | q;
    }
}

// --- aggregation inner body (one node, one 32-lane group) ------------------
static __device__ __forceinline__ float4 agg_node(const unsigned short* __restrict__ Hb,
                                                  const int* __restrict__ offs,
                                                  const unsigned* __restrict__ spair,
                                                  const float* __restrict__ dinv,
                                                  float4 bv, float alpha,
                                                  int g, int lane) {
    float di = dinv[g];
    float4 acc = bv;
    ushort4 hv = *(const ushort4*)(Hb + (size_t)g * 128 + lane * 4);
    float sw = di * di;
    acc.x += bf2f(hv.x) * sw; acc.y += bf2f(hv.y) * sw;
    acc.z += bf2f(hv.z) * sw; acc.w += bf2f(hv.w) * sw;
    int j0 = offs[g], j1 = offs[g + 1];
    for (int jb = j0; jb < j1; jb += 32) {
        int j = jb + lane;
        unsigned sp = 0u;
        if (j < j1) sp = spair[j];
        int cnt = j1 - jb; if (cnt > 32) cnt = 32;
        int full = cnt & ~3, i = 0;
        for (; i < full; i += 4) {
            unsigned p0 = __shfl(sp, i,     32), p1 = __shfl(sp, i + 1, 32);
            unsigned p2 = __shfl(sp, i + 2, 32), p3 = __shfl(sp, i + 3, 32);
            int   s0 = p0 >> 15, s1 = p1 >> 15, s2 = p2 >> 15, s3 = p3 >> 15;
            float w0 = (float)(p0 & 0x7FFFu) * Q15_INV;
            float w1 = (float)(p1 & 0x7FFFu) * Q15_INV;
            float w2 = (float)(p2 & 0x7FFFu) * Q15_INV;
            float w3 = (float)(p3 & 0x7FFFu) * Q15_INV;
            ushort4 h0 = *(const ushort4*)(Hb + (size_t)s0 * 128 + lane * 4);
            ushort4 h1 = *(const ushort4*)(Hb + (size_t)s1 * 128 + lane * 4);
            ushort4 h2 = *(const ushort4*)(Hb + (size_t)s2 * 128 + lane * 4);
            ushort4 h3 = *(const ushort4*)(Hb + (size_t)s3 * 128 + lane * 4);
            acc.x += bf2f(h0.x) * w0; acc.y += bf2f(h0.y) * w0;
            acc.z += bf2f(h0.z) * w0; acc.w += bf2f(h0.w) * w0;
            acc.x += bf2f(h1.x) * w1; acc.y += bf2f(h1.y) * w1;
            acc.z += bf2f(h1.z) * w1; acc.w += bf2f(h1.w) * w1;
            acc.x += bf2f(h2.x) * w2; acc.y += bf2f(h2.y) * w2;
            acc.z += bf2f(h2.z) * w2; acc.w += bf2f(h2.w) * w2;
            acc.x += bf2f(h3.x) * w3; acc.y += bf2f(h3.y) * w3;
            acc.z += bf2f(h3.z) * w3; acc.w += bf2f(h3.w) * w3;
        }
        for (; i < cnt; ++i) {
            unsigned pv = __shfl(sp, i, 32);
            int   sv = pv >> 15;
            float wv = (float)(pv & 0x7FFFu) * Q15_INV;
            ushort4 h4 = *(const ushort4*)(Hb + (size_t)sv * 128 + lane * 4);
            acc.x += bf2f(h4.x) * wv; acc.y += bf2f(h4.y) * wv;
            acc.z += bf2f(h4.z) * wv; acc.w += bf2f(h4.w) * wv;
        }
    }
    acc.x = acc.x >= 0.f ? acc.x : alpha * acc.x;
    acc.y = acc.y >= 0.f ? acc.y : alpha * acc.y;
    acc.z = acc.z >= 0.f ? acc.z : alpha * acc.z;
    acc.w = acc.w >= 0.f ? acc.w : alpha * acc.w;
    return acc;
}

// --- FUSED: agg(layer1) + gemm2 --------------------------------------------
// Block = 256 thr, 64 nodes. Phase 1: aggregate -> Out1 (fp32) + bf16 rows
// in swizzled LDS. Phase 2: each wave MFMAs 16 rows x 128 cols vs packed W2
// -> Hb2 (separate buffer; Hb still being gathered by other blocks).
__global__ __launch_bounds__(256) void k_agg_gemm(
        const unsigned short* __restrict__ Hb,
        const int* __restrict__ offs,
        const unsigned* __restrict__ spair,
        const float* __restrict__ dinv,
        const float* __restrict__ bias,
        const float* __restrict__ a_ptr,
        const unsigned short* __restrict__ Bp2,
        float* __restrict__ Out1,
        unsigned short* __restrict__ Hb2, int N) {
    __shared__ unsigned short rows[64 * 128];
    int grp = threadIdx.x >> 5, lane5 = threadIdx.x & 31;
    int base = blockIdx.x * 64;
    float alpha = a_ptr[0];
    float4 bv = ld4(bias + lane5 * 4);
    #pragma unroll 2
    for (int t = 0; t < 8; ++t) {
        int lrow = t * 8 + grp;
        int g = base + lrow;
        float4 acc;
        if (g < N) {
            acc = agg_node(Hb, offs, spair, dinv, bv, alpha, g, lane5);
            *(float4*)(Out1 + (size_t)g * 128 + lane5 * 4) = acc;
        } else {
            acc.x = acc.y = acc.z = acc.w = 0.f;
        }
        int sel = (lane5 * 4) ^ ((lrow & 7) << 3);   // swizzle (G4/T2)
        ushort4 rb;
        rb.x = f2bf(acc.x); rb.y = f2bf(acc.y);
        rb.z = f2bf(acc.z); rb.w = f2bf(acc.w);
        *(ushort4*)&rows[lrow * 128 + sel] = rb;
    }
    __syncthreads();
    // Phase 2: wave w owns rows [w*16, w*16+16), K = 128 (KS=4)
    int wave = threadIdx.x >> 6, lane = threadIdx.x & 63;
    int rbase = wave * 16;
    f32x4 acc2[8] = {};
    #pragma unroll
    for (int ks = 0; ks < 4; ++ks) {
        int arow = rbase + (lane & 15);
        int koff = ks * 32 + (lane >> 4) * 8;
        int sidx = koff ^ ((arow & 7) << 3);
        short8v af = *(const short8v*)&rows[arow * 128 + sidx];
        #pragma unroll
        for (int nt = 0; nt < 8; ++nt) {
            short8v bf = *(const short8v*)&Bp2[(((size_t)nt * 4 + ks) * 64 + lane) * 8];
            acc2[nt] = __builtin_amdgcn_mfma_f32_16x16x32_bf16(af, bf, acc2[nt], 0, 0, 0);
        }
    }
    int orow0 = base + rbase + (lane >> 4) * 4;
    #pragma unroll
    for (int nt = 0; nt < 8; ++nt) {
        int col = nt * 16 + (lane & 15);
        #pragma unroll
        for (int j = 0; j < 4; ++j) {
            int r = orow0 + j;
            if (r < N) Hb2[(size_t)r * 128 + col] = f2bf(acc2[nt][j]);
        }
    }
}

// --- plain aggregation (layer 2) + bias + PReLU ----------------------------
__global__ __launch_bounds__(256) void k_agg(const unsigned short* __restrict__ Hb,
                                             const int* __restrict__ offs,
                                             const unsigned* __restrict__ spair,
                                             const float* __restrict__ dinv,
                                             const float* __restrict__ bias,
                                             const float* __restrict__ a_ptr,
                                             float* __restrict__ Out, int N) {
    int g = blockIdx.x * 8 + (threadIdx.x >> 5);
    int lane = threadIdx.x & 31;
    if (g >= N) return;
    float alpha = a_ptr[0];
    float4 bv = ld4(bias + lane * 4);
    float4 acc = agg_node(Hb, offs, spair, dinv, bv, alpha, g, lane);
    *(float4*)(Out + (size_t)g * 128 + lane * 4) = acc;
}

// ---------------------------------------------------------------------------
extern "C" void kernel_launch(void* const* d_in, const int* in_sizes, int n_in,
                              void* d_out, int out_size, void* d_ws, size_t ws_size,
                              hipStream_t stream) {
    const float* x  = (const float*)d_in[0];
    const void*  ei = d_in[1];
    const float* ew = (const float*)d_in[2];
    const float* W1 = (const float*)d_in[3];
    const float* b1 = (const float*)d_in[4];
    const float* W2 = (const float*)d_in[5];
    const float* b2 = (const float*)d_in[6];
    const float* ap = (const float*)d_in[7];
    const int N = in_sizes[0] / 256;
    const int E = in_sizes[2];

    float* out1 = (float*)d_out;
    float* out2 = out1 + (size_t)N * 128;

    char* p = (char*)d_ws;
    auto alloc = [&](size_t bytes) { void* r = (void*)p; p += (bytes + 255) & ~(size_t)255; return r; };
    unsigned* packed = (unsigned*)alloc((size_t)N * 4);
    float* dinv  = (float*)alloc((size_t)N * 4);
    int*   offs  = (int*)  alloc((size_t)(N + 1) * 4);
    int*   bsum  = (int*)  alloc((size_t)((N + 255) / 256) * 4);
    int*   flag  = (int*)  alloc(256);
    unsigned char* rank = (unsigned char*)alloc((size_t)E);
    unsigned* spair = (unsigned*)alloc((size_t)E * 4);
    unsigned short* hb  = (unsigned short*)alloc((size_t)N * 128 * 2);
    unsigned short* hb2 = (unsigned short*)alloc((size_t)N * 128 * 2);
    unsigned short* bp1 = (unsigned short*)alloc((size_t)128 * 256 * 2);
    unsigned short* bp2 = (unsigned short*)alloc((size_t)128 * 128 * 2);

    const int nbN    = (N + 255) / 256;
    const int nbE    = (E + 255) / 256;
    const int nbCnt  = (E + 2047) / 2048;
    const int nbGemm = (N + 127) / 128;
    const int cgrps  = (nbCnt + 7) / 8;
    const int ggrps  = (nbGemm + 7) / 8;

    k_prep<<<nbN + 128 + 64 + 1, 256, 0, stream>>>(packed, N, W1, bp1, W2, bp2,
                                                   (const int*)ei, flag, nbN);
    k_count_gemm1<<<(cgrps + ggrps) * 8, 256, 0, stream>>>(
        ei, ew, flag, packed, rank, E, x, bp1, hb, N, nbCnt, nbGemm, cgrps, ggrps);
    k_blocksum<<<nbN, 256, 0, stream>>>(packed, bsum, N);
    k_scan_bsum<<<1, 512, 0, stream>>>(bsum, nbN);
    k_scan_final<<<nbN, 256, 0, stream>>>(packed, bsum, offs, dinv, N, E);
    k_scatter<<<nbE, 256, 0, stream>>>(ei, ew, flag, dinv, offs, rank, spair, E);

    k_agg_gemm<<<(N + 63) / 64, 256, 0, stream>>>(hb, offs, spair, dinv, b1, ap,
                                                  bp2, out1, hb2, N);
    k_agg<<<(N + 7) / 8, 256, 0, stream>>>(hb2, offs, spair, dinv, b2, ap, out2, N);
}

// Round 13
// 266.765 us; speedup vs baseline: 1.0929x; 1.0929x over previous
//
#include <hip/hip_runtime.h>

// ---------------------------------------------------------------------------
// GCN 2-layer: h1 = prelu(gcn(x,W1,b1)), h2 = prelu(gcn(h1,W2,b2))
// R10 configuration (best measured: 271us) + detect folded into prep.
// CSR build: ONE packed 32-bit returning atomic per edge (count<<24 | deg
// q6.18); ~21 G returning-atomics/s is the fabric RMW service cap (R5-R9).
// Count grid-fused with layer-1 GEMM, group-of-8 interleave. spair packed
// 4B: (src<<15)|q0.15(norm), rank uchar. h stored bf16; LDS-free MFMA
// 16x16x32 bf16 GEMMs with pre-packed weights. Pull aggregation (2 lines
// per edge = minimal), fp32 accum, bias+PReLU fused into the write.
// All phases share the fabric -> additive; measured floor ~270us.
// ---------------------------------------------------------------------------

static __device__ __forceinline__ float4 ld4(const float* p) { return *(const float4*)p; }

static __device__ __forceinline__ unsigned short f2bf(float f) {
    unsigned u = __float_as_uint(f);
    u += 0x7fff + ((u >> 16) & 1);          // round-to-nearest-even
    return (unsigned short)(u >> 16);
}
static __device__ __forceinline__ float bf2f(unsigned short h) {
    return __uint_as_float(((unsigned)h) << 16);
}

typedef __attribute__((ext_vector_type(8))) short short8v;
typedef __attribute__((ext_vector_type(4))) float f32x4;

static __device__ __forceinline__ int eidx(const void* ei, int flag, long long idx) {
    if (flag) return (int)((const long long*)ei)[idx];
    return ((const int*)ei)[idx];
}

#define CNT_SH 24
#define DEG_SCALE 262144.0f            // 2^18
#define DEG_INV   3.814697265625e-06f  // 2^-18
#define Q15_INV   3.0517578125e-05f    // 2^-15

// --- W pack body: fp32 [128][K] -> bf16 B-fragment layout ------------------
static __device__ __forceinline__ void packW_body(const float* __restrict__ W,
                                                  unsigned short* __restrict__ Bp,
                                                  int t, int kbits) {
    int K = 1 << kbits;
    int col = t >> kbits, k = t & (K - 1);
    int nt = col >> 4, ks = k >> 5;
    int lane = (col & 15) | (((k >> 3) & 3) << 4);
    int j = k & 7;
    Bp[((((size_t)nt * (K >> 5) + ks) * 64 + lane) << 3) + j] = f2bf(W[t]);
}

// --- fused prep: init packed[] + pack W1 + pack W2 + detect dtype ----------
__global__ __launch_bounds__(256) void k_prep(unsigned* __restrict__ packed, int N,
                                              const float* __restrict__ W1,
                                              unsigned short* __restrict__ bp1,
                                              const float* __restrict__ W2,
                                              unsigned short* __restrict__ bp2,
                                              const int* __restrict__ ei_raw,
                                              int* __restrict__ flag,
                                              int nbInit) {
    int b = blockIdx.x;
    if (b < nbInit) {
        int i = b * 256 + threadIdx.x;
        if (i < N) packed[i] = 0u;
    } else if (b < nbInit + 128) {
        int t = (b - nbInit) * 256 + threadIdx.x;       // 128*256 elements
        packW_body(W1, bp1, t, 8);
    } else if (b < nbInit + 192) {
        int t = (b - nbInit - 128) * 256 + threadIdx.x; // 128*128 elements
        packW_body(W2, bp2, t, 7);
    } else {
        __shared__ int anynz;
        if (threadIdx.x == 0) anynz = 0;
        __syncthreads();
        if (ei_raw[2 * threadIdx.x + 1] != 0) anynz = 1;
        __syncthreads();
        if (threadIdx.x == 0) *flag = (anynz == 0) ? 1 : 0;
    }
}

// --- count body: 8 packed returning atomics per thread ---------------------
static __device__ __forceinline__ void count_body(const void* __restrict__ ei,
                                                  const float* __restrict__ ew,
                                                  int flag,
                                                  unsigned* __restrict__ packed,
                                                  unsigned char* __restrict__ rank,
                                                  int E, int cbid) {
    int base = cbid * 2048 + threadIdx.x;
    int d[8]; unsigned inc[8]; bool ok[8];
    #pragma unroll
    for (int u = 0; u < 8; ++u) {
        int e = base + u * 256;
        ok[u] = e < E;
        if (ok[u]) {
            d[u] = eidx(ei, flag, (long long)E + e);
            inc[u] = (1u << CNT_SH) | (unsigned)(ew[e] * DEG_SCALE);
        }
    }
    unsigned old[8];
    #pragma unroll
    for (int u = 0; u < 8; ++u)
        if (ok[u]) old[u] = atomicAdd(&packed[d[u]], inc[u]);
    #pragma unroll
    for (int u = 0; u < 8; ++u)
        if (ok[u]) rank[base + u * 256] = (unsigned char)(old[u] >> CNT_SH);
}

// --- GEMM body (256 thr = 4 waves, 128 rows/block, 32 rows/wave) -----------
template <int K>
static __device__ __forceinline__ void gemm_body(const float* __restrict__ X,
                                                 const unsigned short* __restrict__ Bp,
                                                 unsigned short* __restrict__ Hb,
                                                 int M, int gbid) {
    constexpr int KS = K / 32;
    int wave = threadIdx.x >> 6, lane = threadIdx.x & 63;
    int row0 = gbid * 128 + wave * 32;
    int r0 = row0 + (lane & 15);      if (r0 >= M) r0 = M - 1;
    int r1 = row0 + 16 + (lane & 15); if (r1 >= M) r1 = M - 1;
    int kc = (lane >> 4) * 8;
    const float* x0 = X + (size_t)r0 * K + kc;
    const float* x1 = X + (size_t)r1 * K + kc;

    f32x4 acc[2][8] = {};
    #pragma unroll 2
    for (int ks = 0; ks < KS; ++ks) {
        float4 a0 = ld4(x0 + ks * 32), a1 = ld4(x0 + ks * 32 + 4);
        float4 c0 = ld4(x1 + ks * 32), c1 = ld4(x1 + ks * 32 + 4);
        short8v af0, af1;
        af0[0] = (short)f2bf(a0.x); af0[1] = (short)f2bf(a0.y);
        af0[2] = (short)f2bf(a0.z); af0[3] = (short)f2bf(a0.w);
        af0[4] = (short)f2bf(a1.x); af0[5] = (short)f2bf(a1.y);
        af0[6] = (short)f2bf(a1.z); af0[7] = (short)f2bf(a1.w);
        af1[0] = (short)f2bf(c0.x); af1[1] = (short)f2bf(c0.y);
        af1[2] = (short)f2bf(c0.z); af1[3] = (short)f2bf(c0.w);
        af1[4] = (short)f2bf(c1.x); af1[5] = (short)f2bf(c1.y);
        af1[6] = (short)f2bf(c1.z); af1[7] = (short)f2bf(c1.w);
        #pragma unroll
        for (int nt = 0; nt < 8; ++nt) {
            short8v bf = *(const short8v*)&Bp[(((size_t)nt * KS + ks) * 64 + lane) * 8];
            acc[0][nt] = __builtin_amdgcn_mfma_f32_16x16x32_bf16(af0, bf, acc[0][nt], 0, 0, 0);
            acc[1][nt] = __builtin_amdgcn_mfma_f32_16x16x32_bf16(af1, bf, acc[1][nt], 0, 0, 0);
        }
    }
    // C/D: col = lane&15, row = (lane>>4)*4 + reg   [m89-verified]
    #pragma unroll
    for (int rg = 0; rg < 2; ++rg) {
        int orow0 = row0 + rg * 16 + (lane >> 4) * 4;
        #pragma unroll
        for (int nt = 0; nt < 8; ++nt) {
            int col = nt * 16 + (lane & 15);
            #pragma unroll
            for (int j = 0; j < 4; ++j) {
                int r = orow0 + j;
                if (r < M) Hb[(size_t)r * 128 + col] = f2bf(acc[rg][nt][j]);
            }
        }
    }
}

// --- fused + interleaved: count || layer-1 GEMM ----------------------------
__global__ __launch_bounds__(256) void k_count_gemm1(
        const void* __restrict__ ei, const float* __restrict__ ew,
        const int* __restrict__ flagp, unsigned* __restrict__ packed,
        unsigned char* __restrict__ rank, int E,
        const float* __restrict__ X, const unsigned short* __restrict__ Bp,
        unsigned short* __restrict__ Hb, int M,
        int nbCount, int nbGemm, int cgrps, int ggrps) {
    int grp = blockIdx.x >> 3, ln = blockIdx.x & 7;
    int tot = cgrps + ggrps;
    int cb = (int)(((long long)grp * cgrps) / tot);
    int ca = (int)(((long long)(grp + 1) * cgrps) / tot);
    if (ca > cb) {
        int id = cb * 8 + ln;
        if (id < nbCount) count_body(ei, ew, *flagp, packed, rank, E, id);
    } else {
        int id = (grp - cb) * 8 + ln;
        if (id < nbGemm) gemm_body<256>(X, Bp, Hb, M, id);
    }
}

__global__ __launch_bounds__(256) void k_gemm2(const float* __restrict__ X,
                                               const unsigned short* __restrict__ Bp,
                                               unsigned short* __restrict__ Hb, int M) {
    gemm_body<128>(X, Bp, Hb, M, blockIdx.x);
}

// --- scan of counts --------------------------------------------------------
__global__ __launch_bounds__(256) void k_blocksum(const unsigned* packed,
                                                  int* bsum, int N) {
    int i = blockIdx.x * 256 + threadIdx.x;
    int v = i < N ? (int)(packed[i] >> CNT_SH) : 0;
    for (int d = 32; d > 0; d >>= 1) v += __shfl_down(v, d, 64);
    __shared__ int wsum[4];
    int lane = threadIdx.x & 63, wid = threadIdx.x >> 6;
    if (lane == 0) wsum[wid] = v;
    __syncthreads();
    if (threadIdx.x == 0) bsum[blockIdx.x] = wsum[0] + wsum[1] + wsum[2] + wsum[3];
}

__global__ __launch_bounds__(512) void k_scan_bsum(int* bsum, int nb) {
    int t = threadIdx.x;
    int v = (t < nb) ? bsum[t] : 0;
    int orig = v;
    int lane = t & 63, wid = t >> 6;
    for (int d = 1; d < 64; d <<= 1) { int n = __shfl_up(v, d, 64); if (lane >= d) v += n; }
    __shared__ int wsum[8];
    if (lane == 63) wsum[wid] = v;
    __syncthreads();
    int woff = 0;
    for (int w = 0; w < 8; ++w) if (w < wid) woff += wsum[w];
    if (t < nb) bsum[t] = v - orig + woff;   // exclusive
}

// scan_final + dinv fused (same index space)
__global__ __launch_bounds__(256) void k_scan_final(const unsigned* packed,
                                                    const int* bsum,
                                                    int* offs, float* dinv,
                                                    int N, int E) {
    int b = blockIdx.x, t = threadIdx.x;
    int i = b * 256 + t;
    unsigned pk = (i < N) ? packed[i] : 0u;
    int v = (int)(pk >> CNT_SH);
    int orig = v;
    int lane = t & 63, wid = t >> 6;
    for (int d = 1; d < 64; d <<= 1) { int n = __shfl_up(v, d, 64); if (lane >= d) v += n; }
    __shared__ int wsum[4];
    if (lane == 63) wsum[wid] = v;
    __syncthreads();
    int woff = bsum[b];
    for (int w = 0; w < 4; ++w) if (w < wid) woff += wsum[w];
    if (i < N) {
        offs[i] = v - orig + woff;
        float dg = 1.0f + (float)(pk & 0xFFFFFFu) * DEG_INV;
        dinv[i] = rsqrtf(dg);
    }
    if (i == 0) offs[N] = E;
}

// --- atomic-free scatter: spair[offs[dst]+rank[e]] = (src<<15)|q15(norm) ---
__global__ __launch_bounds__(256) void k_scatter(const void* __restrict__ ei,
                                                 const float* __restrict__ ew,
                                                 const int* __restrict__ flagp,
                                                 const float* __restrict__ dinv,
                                                 const int* __restrict__ offs,
                                                 const unsigned char* __restrict__ rank,
                                                 unsigned* __restrict__ spair, int E) {
    const int flag = *flagp;
    int e = blockIdx.x * 256 + threadIdx.x;
    if (e < E) {
        int s = eidx(ei, flag, e);
        int d = eidx(ei, flag, (long long)E + e);
        int p = offs[d] + (int)rank[e];
        float nrm = dinv[s] * ew[e] * dinv[d];      // < 0.71 analytically
        unsigned q = (unsigned)(nrm * 32768.0f + 0.5f);
        spair[p] = ((unsigned)s << 15) | q;
    }
}

// --- pull aggregation (bf16 rows) + bias + PReLU ---------------------------
__global__ __launch_bounds__(256) void k_agg(const unsigned short* __restrict__ Hb,
                                             const int* __restrict__ offs,
                                             const unsigned* __restrict__ spair,
                                             const float* __restrict__ dinv,
                                             const float* __restrict__ bias,
                                             const float* __restrict__ a_ptr,
                                             float* __restrict__ Out, int N) {
    int g = blockIdx.x * 8 + (threadIdx.x >> 5);
    int lane = threadIdx.x & 31;
    if (g >= N) return;
    float alpha = a_ptr[0];
    float di = dinv[g];
    float4 acc = ld4(bias + lane * 4);
    ushort4 hv = *(const ushort4*)(Hb + (size_t)g * 128 + lane * 4);
    float sw = di * di;
    acc.x += bf2f(hv.x) * sw; acc.y += bf2f(hv.y) * sw;
    acc.z += bf2f(hv.z) * sw; acc.w += bf2f(hv.w) * sw;
    int j0 = offs[g], j1 = offs[g + 1];
    for (int jb = j0; jb < j1; jb += 32) {
        int j = jb + lane;
        unsigned sp = 0u;                       // s=0, w=0 for pad lanes
        if (j < j1) sp = spair[j];
        int cnt = j1 - jb; if (cnt > 32) cnt = 32;
        int full = cnt & ~3, i = 0;
        for (; i < full; i += 4) {
            unsigned p0 = __shfl(sp, i,     32), p1 = __shfl(sp, i + 1, 32);
            unsigned p2 = __shfl(sp, i + 2, 32), p3 = __shfl(sp, i + 3, 32);
            int   s0 = p0 >> 15, s1 = p1 >> 15, s2 = p2 >> 15, s3 = p3 >> 15;
            float w0 = (float)(p0 & 0x7FFFu) * Q15_INV;
            float w1 = (float)(p1 & 0x7FFFu) * Q15_INV;
            float w2 = (float)(p2 & 0x7FFFu) * Q15_INV;
            float w3 = (float)(p3 & 0x7FFFu) * Q15_INV;
            ushort4 h0 = *(const ushort4*)(Hb + (size_t)s0 * 128 + lane * 4);
            ushort4 h1 = *(const ushort4*)(Hb + (size_t)s1 * 128 + lane * 4);
            ushort4 h2 = *(const ushort4*)(Hb + (size_t)s2 * 128 + lane * 4);
            ushort4 h3 = *(const ushort4*)(Hb + (size_t)s3 * 128 + lane * 4);
            acc.x += bf2f(h0.x) * w0; acc.y += bf2f(h0.y) * w0;
            acc.z += bf2f(h0.z) * w0; acc.w += bf2f(h0.w) * w0;
            acc.x += bf2f(h1.x) * w1; acc.y += bf2f(h1.y) * w1;
            acc.z += bf2f(h1.z) * w1; acc.w += bf2f(h1.w) * w1;
            acc.x += bf2f(h2.x) * w2; acc.y += bf2f(h2.y) * w2;
            acc.z += bf2f(h2.z) * w2; acc.w += bf2f(h2.w) * w2;
            acc.x += bf2f(h3.x) * w3; acc.y += bf2f(h3.y) * w3;
            acc.z += bf2f(h3.z) * w3; acc.w += bf2f(h3.w) * w3;
        }
        for (; i < cnt; ++i) {
            unsigned pv = __shfl(sp, i, 32);
            int   sv = pv >> 15;
            float wv = (float)(pv & 0x7FFFu) * Q15_INV;
            ushort4 h4 = *(const ushort4*)(Hb + (size_t)sv * 128 + lane * 4);
            acc.x += bf2f(h4.x) * wv; acc.y += bf2f(h4.y) * wv;
            acc.z += bf2f(h4.z) * wv; acc.w += bf2f(h4.w) * wv;
        }
    }
    acc.x = acc.x >= 0.f ? acc.x : alpha * acc.x;
    acc.y = acc.y >= 0.f ? acc.y : alpha * acc.y;
    acc.z = acc.z >= 0.f ? acc.z : alpha * acc.z;
    acc.w = acc.w >= 0.f ? acc.w : alpha * acc.w;
    *(float4*)(Out + (size_t)g * 128 + lane * 4) = acc;
}

// ---------------------------------------------------------------------------
extern "C" void kernel_launch(void* const* d_in, const int* in_sizes, int n_in,
                              void* d_out, int out_size, void* d_ws, size_t ws_size,
                              hipStream_t stream) {
    const float* x  = (const float*)d_in[0];
    const void*  ei = d_in[1];
    const float* ew = (const float*)d_in[2];
    const float* W1 = (const float*)d_in[3];
    const float* b1 = (const float*)d_in[4];
    const float* W2 = (const float*)d_in[5];
    const float* b2 = (const float*)d_in[6];
    const float* ap = (const float*)d_in[7];
    const int N = in_sizes[0] / 256;
    const int E = in_sizes[2];

    float* out1 = (float*)d_out;
    float* out2 = out1 + (size_t)N * 128;

    char* p = (char*)d_ws;
    auto alloc = [&](size_t bytes) { void* r = (void*)p; p += (bytes + 255) & ~(size_t)255; return r; };
    unsigned* packed = (unsigned*)alloc((size_t)N * 4);
    float* dinv  = (float*)alloc((size_t)N * 4);
    int*   offs  = (int*)  alloc((size_t)(N + 1) * 4);
    int*   bsum  = (int*)  alloc((size_t)((N + 255) / 256) * 4);
    int*   flag  = (int*)  alloc(256);
    unsigned char* rank = (unsigned char*)alloc((size_t)E);
    unsigned* spair = (unsigned*)alloc((size_t)E * 4);
    unsigned short* hb  = (unsigned short*)alloc((size_t)N * 128 * 2);
    unsigned short* bp1 = (unsigned short*)alloc((size_t)128 * 256 * 2);
    unsigned short* bp2 = (unsigned short*)alloc((size_t)128 * 128 * 2);

    const int nbN    = (N + 255) / 256;
    const int nbE    = (E + 255) / 256;
    const int nbCnt  = (E + 2047) / 2048;
    const int nbGemm = (N + 127) / 128;
    const int cgrps  = (nbCnt + 7) / 8;
    const int ggrps  = (nbGemm + 7) / 8;

    k_prep<<<nbN + 128 + 64 + 1, 256, 0, stream>>>(packed, N, W1, bp1, W2, bp2,
                                                   (const int*)ei, flag, nbN);
    k_count_gemm1<<<(cgrps + ggrps) * 8, 256, 0, stream>>>(
        ei, ew, flag, packed, rank, E, x, bp1, hb, N, nbCnt, nbGemm, cgrps, ggrps);
    k_blocksum<<<nbN, 256, 0, stream>>>(packed, bsum, N);
    k_scan_bsum<<<1, 512, 0, stream>>>(bsum, nbN);
    k_scan_final<<<nbN, 256, 0, stream>>>(packed, bsum, offs, dinv, N, E);
    k_scatter<<<nbE, 256, 0, stream>>>(ei, ew, flag, dinv, offs, rank, spair, E);

    k_agg<<<(N + 7) / 8, 256, 0, stream>>>(hb, offs, spair, dinv, b1, ap, out1, N);
    k_gemm2<<<nbGemm, 256, 0, stream>>>(out1, bp2, hb, N);
    k_agg<<<(N + 7) / 8, 256, 0, stream>>>(hb, offs, spair, dinv, b2, ap, out2, N);
}